// Round 2
// baseline (486.309 us; speedup 1.0000x reference)
//
#include <hip/hip_runtime.h>
#include <math.h>

#define NSEQ 2048
#define EPSF 1e-8f
#define INV2R2 0.35355339059327373f
#define INVR2  0.7071067811865476f

// ---------- compile-time Leray conv taps ----------
// Jacobi: p_{n+1} = M p_n - 0.5 b, M = avg(neighbors), p_0 = 0, 50 iters
// => p = K * b, K = -0.5 * sum_{i=0}^{49} M^i   (circulant, support |j|<=49)
// leray(u) = u - grad1(K * div1(u)) = conv(LK, u); LK symmetric -> self-adjoint.
struct TapsF { float v[101]; };

constexpr TapsF make_tapsf() {
  TapsF t{};
  double K[99] = {};
  for (int j = -49; j <= 49; ++j) {
    int aj = j < 0 ? -j : j;
    double term = 1.0;
    for (int q = 0; q < aj; ++q) term *= 0.5;
    double sum = term;
    for (int i = aj + 2; i <= 49; i += 2) {
      int m = (i + j) / 2;
      term *= (double)((i - 1) * i) / (4.0 * (double)m * (double)(i - m));
      sum += term;
    }
    K[j + 49] = -0.5 * sum;
  }
  for (int o = -50; o <= 50; ++o) {
    double km1 = (o - 1 >= -49 && o - 1 <= 49) ? K[o - 1 + 49] : 0.0;
    double k0  = (o     >= -49 && o     <= 49) ? K[o + 49]     : 0.0;
    double kp1 = (o + 1 >= -49 && o + 1 <= 49) ? K[o + 1 + 49] : 0.0;
    double T = kp1 - 2.0 * k0 + km1;
    t.v[o + 50] = (float)(((o == 0) ? 1.0 : 0.0) - T);
  }
  return t;
}
constexpr TapsF LKF = make_tapsf();

// ---------- reduction helpers (1024 threads = 16 waves) ----------
__device__ __forceinline__ float wave_sum(float x) {
#pragma unroll
  for (int m = 1; m < 64; m <<= 1) x += __shfl_xor(x, m, 64);
  return x;
}
__device__ __forceinline__ float wave_max(float x) {
#pragma unroll
  for (int m = 1; m < 64; m <<= 1) x = fmaxf(x, __shfl_xor(x, m, 64));
  return x;
}
__device__ __forceinline__ float block_sum(float x, float* red, int tid, int& gen) {
  float w = wave_sum(x);
  int slot = (gen & 7) << 5; gen++;
  if ((tid & 63) == 0) red[slot + (tid >> 6)] = w;
  __syncthreads();
  float s = 0.f;
#pragma unroll
  for (int q = 0; q < 16; ++q) s += red[slot + q];
  return s;
}
__device__ __forceinline__ void block_sum2(float a, float b, float* red, int tid, int& gen,
                                           float& oa, float& ob) {
  float wa = wave_sum(a), wb = wave_sum(b);
  int slot = (gen & 7) << 5; gen++;
  if ((tid & 63) == 0) { int w = tid >> 6; red[slot + w] = wa; red[slot + 16 + w] = wb; }
  __syncthreads();
  float sa = 0.f, sb = 0.f;
#pragma unroll
  for (int q = 0; q < 16; ++q) { sa += red[slot + q]; sb += red[slot + 16 + q]; }
  oa = sa; ob = sb;
}

// ---------- 101-tap circular conv, XOR-swizzled transposed staging ----------
// layout: swaddr(i) = ((i&7)<<8) | ((i>>3) ^ ((i&7)<<2))  -> stage R/W and
// window reads are all <=2-way bank aliased (free on CDNA4).
// Compute phase runs on waves 0-3 (tid<256), 8 outputs/thread (min LDS instrs).
template <int MODE, bool DO_MAX>  // MODE 0: dst=conv(src); 1: dst -= 0.1*conv(src)
__device__ __forceinline__ void conv_apply(float* __restrict__ dst, const float* __restrict__ src,
                                           float* __restrict__ cb, float* __restrict__ red2,
                                           int tid) {
  __syncthreads();
#pragma unroll
  for (int m = 0; m < 2; ++m) {
    int i = tid + 1024 * m;
    int a = ((i & 7) << 8) | ((i >> 3) ^ ((i & 7) << 2));
    cb[a] = src[i];
  }
  __syncthreads();
  if (tid < 256) {
    const int base = tid << 3;
    const int c0 = tid - 7;          // (base-50)>>3
    float acc[8] = {0.f, 0.f, 0.f, 0.f, 0.f, 0.f, 0.f, 0.f};
#pragma unroll
    for (int r = 0; r < 8; ++r) {
      const int R = r << 8, K = r << 2;
#pragma unroll
      for (int m = 0; m < 15; ++m) {
        // value i = base - 56 + 8m + r; tap idx for out j: ti = 106 + j - 8m - r
        if (8 * m + r >= 6 && 8 * m + r <= 113) {
          int cc = (c0 + m) & 255;
          float val = cb[R | (cc ^ K)];
#pragma unroll
          for (int j = 0; j < 8; ++j) {
            const int ti = 106 + j - 8 * m - r;
            if (ti >= 0 && ti <= 100) acc[j] = fmaf(LKF.v[ti], val, acc[j]);
          }
        }
      }
    }
    if (MODE == 0) {
      *(float4*)(dst + base)     = make_float4(acc[0], acc[1], acc[2], acc[3]);
      *(float4*)(dst + base + 4) = make_float4(acc[4], acc[5], acc[6], acc[7]);
    } else {
      float4 d0 = *(float4*)(dst + base);
      float4 d1 = *(float4*)(dst + base + 4);
      d0.x -= 0.1f * acc[0]; d0.y -= 0.1f * acc[1]; d0.z -= 0.1f * acc[2]; d0.w -= 0.1f * acc[3];
      d1.x -= 0.1f * acc[4]; d1.y -= 0.1f * acc[5]; d1.z -= 0.1f * acc[6]; d1.w -= 0.1f * acc[7];
      *(float4*)(dst + base)     = d0;
      *(float4*)(dst + base + 4) = d1;
    }
    if (DO_MAX) {
      float mm = 0.f;
#pragma unroll
      for (int j = 0; j < 8; ++j) mm = fmaxf(mm, fabsf(acc[j]));
      mm = wave_max(mm);
      if ((tid & 63) == 0) red2[tid >> 6] = mm;
    }
  }
  __syncthreads();
}

// ---------- kernel A: rho_unscaled (L2 of DWT rows) + per_token ----------
__global__ __launch_bounds__(256) void kA(const float* __restrict__ x,
                                          const float* __restrict__ wv,
                                          float* __restrict__ rho_us,
                                          float* __restrict__ pt) {
  const int blk = blockIdx.x;
  const int b = blk >> 8;
  const int g = blk & 255;
  const float* xb = x + (((size_t)b * NSEQ) + (size_t)g * 8) * 2048;
  const int tid = threadIdx.x;
  float sq[8] = {0.f, 0.f, 0.f, 0.f, 0.f, 0.f, 0.f, 0.f};
  float pp[8] = {0.f, 0.f, 0.f, 0.f, 0.f, 0.f, 0.f, 0.f};
  for (int c = tid * 4; c < 2048; c += 1024) {
    float4 w4 = *(const float4*)(wv + c);
    float wj[4] = {w4.x, w4.y, w4.z, w4.w};
    float xv[8][4];
#pragma unroll
    for (int r = 0; r < 8; ++r) {
      float4 t = *(const float4*)(xb + (size_t)r * 2048 + c);
      xv[r][0] = t.x; xv[r][1] = t.y; xv[r][2] = t.z; xv[r][3] = t.w;
    }
#pragma unroll
    for (int j = 0; j < 4; ++j) {
      float x0 = xv[0][j], x1 = xv[1][j], x2 = xv[2][j], x3 = xv[3][j];
      float x4 = xv[4][j], x5 = xv[5][j], x6 = xv[6][j], x7 = xv[7][j];
      float t01 = x0 + x1, t23 = x2 + x3, t45 = x4 + x5, t67 = x6 + x7;
      float a = t01 + t23, bb = t45 + t67;
      float c3 = a + bb, d3 = a - bb, d2a = t01 - t23, d2b = t45 - t67;
      float d10 = x0 - x1, d11 = x2 - x3, d12 = x4 - x5, d13 = x6 - x7;
      sq[0] += c3 * c3;  sq[1] += d3 * d3;  sq[2] += d2a * d2a; sq[3] += d2b * d2b;
      sq[4] += d10 * d10; sq[5] += d11 * d11; sq[6] += d12 * d12; sq[7] += d13 * d13;
      float w = wj[j];
      pp[0] += x0 * w; pp[1] += x1 * w; pp[2] += x2 * w; pp[3] += x3 * w;
      pp[4] += x4 * w; pp[5] += x5 * w; pp[6] += x6 * w; pp[7] += x7 * w;
    }
  }
  __shared__ float sred[4][16];
  float vals[16];
#pragma unroll
  for (int q = 0; q < 8; ++q) vals[q] = sq[q];
#pragma unroll
  for (int q = 0; q < 8; ++q) vals[8 + q] = pp[q];
#pragma unroll
  for (int q = 0; q < 16; ++q) vals[q] = wave_sum(vals[q]);
  int lane = tid & 63, wid = tid >> 6;
  if (lane == 0) {
#pragma unroll
    for (int q = 0; q < 16; ++q) sred[wid][q] = vals[q];
  }
  __syncthreads();
  if (tid < 16) {
    float s = sred[0][tid] + sred[1][tid] + sred[2][tid] + sred[3][tid];
    if (tid < 8) {
      float scale = (tid < 2) ? 0.125f : ((tid < 4) ? 0.25f : 0.5f);
      int pos = (tid == 0) ? g : (tid == 1) ? (256 + g)
               : (tid < 4) ? (512 + 2 * g + (tid - 2)) : (1024 + 4 * g + (tid - 4));
      rho_us[b * NSEQ + pos] = sqrtf(s * scale);
    } else {
      pt[b * NSEQ + 8 * g + (tid - 8)] = s;
    }
  }
}

// ---------- kernel B: serial dynamics, one 1024-thread block per batch ----------
__global__ __launch_bounds__(1024, 4) void kB(const float* __restrict__ rho_us,
                                              const float* __restrict__ pt,
                                              const float* __restrict__ phi,
                                              float* __restrict__ rho_f) {
  extern __shared__ float sm[];
  float* v    = sm;
  float* rho  = sm + NSEQ;
  float* u    = sm + 2 * NSEQ;
  float* up   = sm + 3 * NSEQ;
  float* y0   = sm + 4 * NSEQ;
  float* y1   = sm + 5 * NSEQ;
  float* y2   = sm + 6 * NSEQ;
  float* y3   = sm + 7 * NSEQ;
  float* yb   = sm + 8 * NSEQ;
  float* cb   = sm + 9 * NSEQ;
  float* red  = sm + 10 * NSEQ;   // 256 floats
  float* red2 = red + 256;        // 4 floats
  const int tid = threadIdx.x;
  const int b = blockIdx.x;
  int gen = 0;
  const float CFL_ = 0.4f;

  // ---- v = normalize(|dwt1d(per_token)| * sqrt(D)) ----
  {
    const float* ptb = pt + b * NSEQ;
    float vl[2]; float part = 0.f;
    {  // m=0: s = tid in [0,1024): a3 / d3 / d2
      int s = tid; float c;
      if (s < 256) {
        int r = s * 8;
        float t01 = ptb[r] + ptb[r+1], t23 = ptb[r+2] + ptb[r+3];
        float t45 = ptb[r+4] + ptb[r+5], t67 = ptb[r+6] + ptb[r+7];
        c = ((t01 + t23) + (t45 + t67)) * INV2R2;
      } else if (s < 512) {
        int r = (s - 256) * 8;
        float t01 = ptb[r] + ptb[r+1], t23 = ptb[r+2] + ptb[r+3];
        float t45 = ptb[r+4] + ptb[r+5], t67 = ptb[r+6] + ptb[r+7];
        c = ((t01 + t23) - (t45 + t67)) * INV2R2;
      } else {
        int r = (s - 512) * 4;
        c = ((ptb[r] + ptb[r+1]) - (ptb[r+2] + ptb[r+3])) * 0.5f;
      }
      float val = sqrtf(2048.0f * c * c) + EPSF;
      vl[0] = val; part += val;
    }
    {  // m=1: s = tid+1024: d1
      int r = tid * 2;
      float c = (ptb[r] - ptb[r+1]) * INVR2;
      float val = sqrtf(2048.0f * c * c) + EPSF;
      vl[1] = val; part += val;
    }
    float sv = block_sum(part, red, tid, gen);
    float inv = 1.0f / sv;
    v[tid] = vl[0] * inv; v[tid + 1024] = vl[1] * inv;
  }
  // ---- rho = normalize(rho_us) ----
  {
    const float* rb = rho_us + b * NSEQ;
    float rl[2]; float part = 0.f;
#pragma unroll
    for (int m = 0; m < 2; ++m) { float r = rb[tid + 1024 * m] + EPSF; rl[m] = r; part += r; }
    float sr = block_sum(part, red, tid, gen);
    float inv = 1.f / sr;
#pragma unroll
    for (int m = 0; m < 2; ++m) rho[tid + 1024 * m] = rl[m] * inv;
  }
  __syncthreads();

  for (int k = 0; k < 3; ++k) {
    // ---- reaction ----
    {
      float tl[2]; float part = 0.f;
#pragma unroll
      for (int m = 0; m < 2; ++m) {
        int i = tid + 1024 * m;
        float r = rho[i];
        float t = r * expf(-0.1f * (phi[i] + logf(r)));
        float t2 = fabsf(t) + EPSF;
        tl[m] = t2; part += t2;
      }
      float s = block_sum(part, red, tid, gen);
      float inv = 1.f / s;
#pragma unroll
      for (int m = 0; m < 2; ++m) rho[tid + 1024 * m] = tl[m] * inv;
    }
    // ---- mpc: u = grad1(v) ----
#pragma unroll
    for (int m = 0; m < 2; ++m) {
      int i = tid + 1024 * m; int ip1 = (i + 1) & (NSEQ - 1);
      u[i] = v[ip1] - v[i];
    }
    for (int step = 0; step < 5; ++step) {
      conv_apply<0, true>(up, u, cb, red2, tid);   // up = leray(u), wave-max folded
      float mx = fmaxf(fmaxf(red2[0], red2[1]), fmaxf(red2[2], red2[3]));
      float dt = CFL_ / (mx + EPSF);
      // ---- forward rollout (ntie folded into t=0, wbar.r4 dot into t=3) ----
      float sarr[4]; float spv = 1.f; float ntie = 1.f, dot = 0.f;
#pragma unroll
      for (int t = 0; t < 4; ++t) {
        const float* yp = (t == 1) ? y0 : (t == 2) ? y1 : y2;
        float* yw = (t == 0) ? y0 : (t == 1) ? y1 : (t == 2) ? y2 : y3;
        float invp = 1.f / spv;
        float part2 = 0.f, aux = 0.f;
#pragma unroll
        for (int m = 0; m < 2; ++m) {
          int i = tid + 1024 * m, im1 = (i - 1) & (NSEQ - 1), ip1 = (i + 1) & (NSEQ - 1);
          float ri, rim1, rip1;
          if (t == 0) { ri = rho[i]; rim1 = rho[im1]; rip1 = rho[ip1]; }
          else {
            ri   = (fabsf(yp[i])   + EPSF) * invp;
            rim1 = (fabsf(yp[im1]) + EPSF) * invp;
            rip1 = (fabsf(yp[ip1]) + EPSF) * invp;
          }
          float ui = up[i], um = up[im1];
          float Fi = ui > 0.f ? ui * ri : ui * rip1;
          float Fm = um > 0.f ? um * rim1 : um * ri;
          float yv = ri - dt * (Fi - Fm);
          yw[i] = yv;
          float ayv = fabsf(yv) + EPSF;
          part2 += ayv;
          if (t == 0) aux += (fabsf(ui) == mx) ? 1.f : 0.f;
          if (t == 3) aux += (1.f - v[i]) * 0.125f * ayv;
        }
        if (t == 0) { float o1, o2; block_sum2(part2, aux, red, tid, gen, o1, o2); sarr[0] = o1; ntie = o2; }
        else if (t == 3) { float o1, o2; block_sum2(part2, aux, red, tid, gen, o1, o2); sarr[3] = o1; dot = o2 / o1; }
        else sarr[t] = block_sum(part2, red, tid, gen);
        spv = sarr[t];
      }
      // ---- backward ----
      float wreg[2], upbar[2];
      upbar[0] = 0.f; upbar[1] = 0.f;
#pragma unroll
      for (int m = 0; m < 2; ++m) wreg[m] = (1.f - v[tid + 1024 * m]) * 0.125f;
      float dtb_part = 0.f;
#pragma unroll
      for (int t = 3; t >= 0; --t) {
        const float* yt = (t == 0) ? y0 : (t == 1) ? y1 : (t == 2) ? y2 : y3;
        const float* yp = (t == 1) ? y0 : (t == 2) ? y1 : y2;
        float invst = 1.f / sarr[t];
        float invp = (t > 0) ? 1.f / sarr[t - 1] : 0.f;
        // pass A: ybar
#pragma unroll
        for (int m = 0; m < 2; ++m) {
          int i = tid + 1024 * m;
          float yv = yt[i];
          float sg = (yv > 0.f) ? 1.f : ((yv < 0.f) ? -1.f : 0.f);
          yb[i] = sg * (wreg[m] - dot) * invst;
        }
        __syncthreads();
        // pass B: new wbar, upbar, dtbar, next dot
        float dotn = 0.f;
#pragma unroll
        for (int m = 0; m < 2; ++m) {
          int i = tid + 1024 * m, im1 = (i - 1) & (NSEQ - 1), ip1 = (i + 1) & (NSEQ - 1);
          float ri, rim1, rip1;
          if (t == 0) { ri = rho[i]; rim1 = rho[im1]; rip1 = rho[ip1]; }
          else {
            ri   = (fabsf(yp[i])   + EPSF) * invp;
            rim1 = (fabsf(yp[im1]) + EPSF) * invp;
            rip1 = (fabsf(yp[ip1]) + EPSF) * invp;
          }
          float ui = up[i], um = up[im1];
          float ybi = yb[i], ybm = yb[im1], ybp = yb[ip1];
          float Fbi = dt * (ybp - ybi);
          float Fbm = dt * (ybi - ybm);
          float wn = ybi;
          if (ui > 0.f)    wn += Fbi * ui;
          if (!(um > 0.f)) wn += Fbm * um;
          upbar[m] += Fbi * (ui > 0.f ? ri : rip1);
          float Fi = ui > 0.f ? ui * ri : ui * rip1;
          float Fm = um > 0.f ? um * rim1 : um * ri;
          dtb_part -= ybi * (Fi - Fm);
          if (t > 0) dotn += wn * ri;
          wreg[m] = wn;
        }
        if (t > 0) dot = block_sum(dotn, red, tid, gen);
      }
      float dtbar = block_sum(dtb_part, red, tid, gen);
      float md = mx + EPSF;
      float mbar = dtbar * (-CFL_ / (md * md));
      float tiesc = mbar / ntie;
#pragma unroll
      for (int m = 0; m < 2; ++m) {
        int i = tid + 1024 * m;
        float ui = up[i];
        if (fabsf(ui) == mx) {
          float sg = (ui > 0.f) ? 1.f : ((ui < 0.f) ? -1.f : 0.f);
          upbar[m] += tiesc * sg;
        }
        yb[i] = upbar[m];
      }
      conv_apply<1, false>(u, yb, cb, red2, tid);  // u -= 0.1 * leray(upbar)
    }
    // ---- outer: u = leray(u); dt; rho = normalize(advect(rho,u,dt,kappa)) ----
    conv_apply<0, true>(up, u, cb, red2, tid);
    float mx = fmaxf(fmaxf(red2[0], red2[1]), fmaxf(red2[2], red2[3]));
    float dt = CFL_ / (mx + EPSF);
    float kap = (k == 0) ? 0.01f : ((k == 1) ? 0.005f : 0.0f);
    float ylc[2]; float p2 = 0.f;
#pragma unroll
    for (int m = 0; m < 2; ++m) {
      int i = tid + 1024 * m, im1 = (i - 1) & (NSEQ - 1), ip1 = (i + 1) & (NSEQ - 1);
      float ri = rho[i], rim1 = rho[im1], rip1 = rho[ip1];
      float ui = up[i], um = up[im1];
      float Fi = ui > 0.f ? ui * ri : ui * rip1;
      float Fm = um > 0.f ? um * rim1 : um * ri;
      float yv = ri - dt * (Fi - Fm) + kap * dt * (rip1 + rim1 - 2.f * ri);
      ylc[m] = yv; p2 += fabsf(yv) + EPSF;
    }
    float s = block_sum(p2, red, tid, gen);
    float inv = 1.f / s;
#pragma unroll
    for (int m = 0; m < 2; ++m) rho[tid + 1024 * m] = (fabsf(ylc[m]) + EPSF) * inv;
    __syncthreads();
  }
  // ---- final: rho_f = (rho + 0.1 v)/sum ----
  {
    float fl[2]; float part = 0.f;
#pragma unroll
    for (int m = 0; m < 2; ++m) {
      int i = tid + 1024 * m;
      float f = rho[i] + 0.1f * v[i];
      fl[m] = f; part += f;
    }
    float s = block_sum(part, red, tid, gen);
    float inv = 1.f / s;
#pragma unroll
    for (int m = 0; m < 2; ++m) rho_f[b * NSEQ + tid + 1024 * m] = fl[m] * inv;
  }
}

// ---------- kernel C: out = IDWT3(rho_f[:,:,None] * band_w[BAND_IDX]) ----------
__global__ __launch_bounds__(256) void kC(const float* __restrict__ rho_f,
                                          const float* __restrict__ bw,
                                          float* __restrict__ out) {
  const int blk = blockIdx.x;
  const int b = blk >> 8;
  const int g = blk & 255;
  __shared__ float q[8];
  if (threadIdx.x < 8) {
    int t = threadIdx.x;
    const float* rb = rho_f + b * NSEQ;
    float val;
    if (t == 0)      val = rb[g] * INV2R2;
    else if (t == 1) val = rb[256 + g] * INV2R2;
    else if (t < 4)  val = rb[512 + 2 * g + (t - 2)] * 0.5f;
    else             val = rb[1024 + 4 * g + (t - 4)] * INVR2;
    q[t] = val;
  }
  __syncthreads();
  float* ob = out + (((size_t)b * NSEQ) + (size_t)g * 8) * 2048;
  for (int c = threadIdx.x * 4; c < 2048; c += 1024) {
    float4 B0 = *(const float4*)(bw + c);
    float4 B1 = *(const float4*)(bw + 2048 + c);
    float4 B2 = *(const float4*)(bw + 4096 + c);
    float4 B3 = *(const float4*)(bw + 6144 + c);
    float b0[4] = {B0.x, B0.y, B0.z, B0.w};
    float b1[4] = {B1.x, B1.y, B1.z, B1.w};
    float b2[4] = {B2.x, B2.y, B2.z, B2.w};
    float b3[4] = {B3.x, B3.y, B3.z, B3.w};
    float o[8][4];
#pragma unroll
    for (int cc = 0; cc < 4; ++cc) {
      float pa = q[0] * b0[cc], pd3 = q[1] * b1[cc];
      float p2a = q[2] * b2[cc], p2b = q[3] * b2[cc];
      float e0 = pa + pd3, e1 = pa - pd3;
      float f0 = e0 + p2a, f1 = e0 - p2a, f2 = e1 + p2b, f3 = e1 - p2b;
      float g0 = q[4] * b3[cc], g1 = q[5] * b3[cc], g2 = q[6] * b3[cc], g3 = q[7] * b3[cc];
      o[0][cc] = f0 + g0; o[1][cc] = f0 - g0;
      o[2][cc] = f1 + g1; o[3][cc] = f1 - g1;
      o[4][cc] = f2 + g2; o[5][cc] = f2 - g2;
      o[6][cc] = f3 + g3; o[7][cc] = f3 - g3;
    }
#pragma unroll
    for (int j = 0; j < 8; ++j) {
      float4 t = make_float4(o[j][0], o[j][1], o[j][2], o[j][3]);
      *(float4*)(ob + (size_t)j * 2048 + c) = t;
    }
  }
}

#define SMEM_B ((10 * NSEQ + 260) * sizeof(float))

extern "C" void kernel_launch(void* const* d_in, const int* in_sizes, int n_in,
                              void* d_out, int out_size, void* d_ws, size_t ws_size,
                              hipStream_t stream) {
  (void)in_sizes; (void)n_in; (void)out_size; (void)ws_size;
  const float* x   = (const float*)d_in[0];
  const float* wv  = (const float*)d_in[1];
  const float* phi = (const float*)d_in[2];
  const float* bw  = (const float*)d_in[3];
  float* out = (float*)d_out;
  float* rho_us = (float*)d_ws;
  float* pt     = rho_us + 8 * NSEQ;
  float* rho_f  = pt + 8 * NSEQ;

  hipFuncSetAttribute((const void*)kB, hipFuncAttributeMaxDynamicSharedMemorySize,
                      (int)SMEM_B);

  kA<<<dim3(2048), dim3(256), 0, stream>>>(x, wv, rho_us, pt);
  kB<<<dim3(8), dim3(1024), SMEM_B, stream>>>(rho_us, pt, phi, rho_f);
  kC<<<dim3(2048), dim3(256), 0, stream>>>(rho_f, bw, out);
}

// Round 3
// 252.979 us; speedup vs baseline: 1.9223x; 1.9223x over previous
//
#include <hip/hip_runtime.h>
#include <math.h>

#define NSEQ 2048
#define EPSF 1e-8f
#define INV2R2 0.35355339059327373f
#define INVR2  0.7071067811865476f

// ---------- compile-time Leray conv taps ----------
// Jacobi: p_{n+1} = M p_n - 0.5 b, M = avg(neighbors), p_0 = 0, 50 iters
// => p = K * b, K = -0.5 * sum_{i=0}^{49} M^i   (circulant, support |j|<=49)
// leray(u) = u - grad1(K * div1(u)) = conv(LK, u); LK symmetric -> self-adjoint.
struct TapsF { float v[101]; };

constexpr TapsF make_tapsf() {
  TapsF t{};
  double K[99] = {};
  for (int j = -49; j <= 49; ++j) {
    int aj = j < 0 ? -j : j;
    double term = 1.0;
    for (int q = 0; q < aj; ++q) term *= 0.5;
    double sum = term;
    for (int i = aj + 2; i <= 49; i += 2) {
      int m = (i + j) / 2;
      term *= (double)((i - 1) * i) / (4.0 * (double)m * (double)(i - m));
      sum += term;
    }
    K[j + 49] = -0.5 * sum;
  }
  for (int o = -50; o <= 50; ++o) {
    double km1 = (o - 1 >= -49 && o - 1 <= 49) ? K[o - 1 + 49] : 0.0;
    double k0  = (o     >= -49 && o     <= 49) ? K[o + 49]     : 0.0;
    double kp1 = (o + 1 >= -49 && o + 1 <= 49) ? K[o + 1 + 49] : 0.0;
    double T = kp1 - 2.0 * k0 + km1;
    t.v[o + 50] = (float)(((o == 0) ? 1.0 : 0.0) - T);
  }
  return t;
}
constexpr TapsF LKF = make_tapsf();

#define NT 512           // kB threads: 8 waves, 2 per SIMD
#define EPT 4            // elements per thread

// ---------- reduction helpers (512 threads = 8 waves) ----------
__device__ __forceinline__ float wave_sum(float x) {
#pragma unroll
  for (int m = 1; m < 64; m <<= 1) x += __shfl_xor(x, m, 64);
  return x;
}
__device__ __forceinline__ float wave_max(float x) {
#pragma unroll
  for (int m = 1; m < 64; m <<= 1) x = fmaxf(x, __shfl_xor(x, m, 64));
  return x;
}
__device__ __forceinline__ float block_sum(float x, float* red, int tid, int& gen) {
  float w = wave_sum(x);
  int slot = (gen & 7) << 5; gen++;
  if ((tid & 63) == 0) red[slot + (tid >> 6)] = w;
  __syncthreads();
  float s = 0.f;
#pragma unroll
  for (int q = 0; q < 8; ++q) s += red[slot + q];
  return s;
}
__device__ __forceinline__ void block_sum2(float a, float b, float* red, int tid, int& gen,
                                           float& oa, float& ob) {
  float wa = wave_sum(a), wb = wave_sum(b);
  int slot = (gen & 7) << 5; gen++;
  if ((tid & 63) == 0) { int w = tid >> 6; red[slot + w] = wa; red[slot + 16 + w] = wb; }
  __syncthreads();
  float sa = 0.f, sb = 0.f;
#pragma unroll
  for (int q = 0; q < 8; ++q) { sa += red[slot + q]; sb += red[slot + 16 + q]; }
  oa = sa; ob = sb;
}

// ---------- 101-tap circular conv, all 512 threads, conflict-free staging ----------
// Value i (i = 4c + r) stored at cb[(r<<9) | (c ^ (r<<3))]:
//  - stage writes: lanes hit 32 distinct banks (verified pattern), conflict-free
//  - window reads: lanes read consecutive c at fixed r -> 2-way (free)
template <int MODE, bool DO_MAX>  // MODE 0: dst=conv(src); 1: dst -= 0.1*conv(src)
__device__ __forceinline__ void conv_apply(float* __restrict__ dst, const float* __restrict__ src,
                                           float* __restrict__ cb, float* __restrict__ red2,
                                           int tid) {
  __syncthreads();
#pragma unroll
  for (int m = 0; m < EPT; ++m) {
    int i = tid + NT * m;
    int a = ((i & 3) << 9) | ((i >> 2) ^ ((i & 3) << 3));
    cb[a] = src[i];
  }
  __syncthreads();
  const int base = tid << 2;
  const int c0 = tid - 13;
  float acc[4] = {0.f, 0.f, 0.f, 0.f};
#pragma unroll
  for (int r = 0; r < 4; ++r) {
    const int R = r << 9, X = r << 3;
#pragma unroll
    for (int m = 0; m < 27; ++m) {
      const int d = 4 * m + r;           // iv = base - 52 + d
      if (d >= 2 && d <= 105) {
        int c = (c0 + m) & 511;
        float val = cb[R | (c ^ X)];
#pragma unroll
        for (int j = 0; j < 4; ++j) {
          const int ti = j + 102 - d;    // tap index for output base+j
          if (ti >= 0 && ti <= 100) acc[j] = fmaf(LKF.v[ti], val, acc[j]);
        }
      }
    }
  }
  if (MODE == 0) {
    *(float4*)(dst + base) = make_float4(acc[0], acc[1], acc[2], acc[3]);
  } else {
    float4 d0 = *(float4*)(dst + base);
    d0.x -= 0.1f * acc[0]; d0.y -= 0.1f * acc[1]; d0.z -= 0.1f * acc[2]; d0.w -= 0.1f * acc[3];
    *(float4*)(dst + base) = d0;
  }
  if (DO_MAX) {
    float mm = fmaxf(fmaxf(fabsf(acc[0]), fabsf(acc[1])), fmaxf(fabsf(acc[2]), fabsf(acc[3])));
    mm = wave_max(mm);
    if ((tid & 63) == 0) red2[tid >> 6] = mm;
  }
  __syncthreads();
}

// ---------- kernel A: rho_unscaled (L2 of DWT rows) + per_token ----------
__global__ __launch_bounds__(256) void kA(const float* __restrict__ x,
                                          const float* __restrict__ wv,
                                          float* __restrict__ rho_us,
                                          float* __restrict__ pt) {
  const int blk = blockIdx.x;
  const int b = blk >> 8;
  const int g = blk & 255;
  const float* xb = x + (((size_t)b * NSEQ) + (size_t)g * 8) * 2048;
  const int tid = threadIdx.x;
  float sq[8] = {0.f, 0.f, 0.f, 0.f, 0.f, 0.f, 0.f, 0.f};
  float pp[8] = {0.f, 0.f, 0.f, 0.f, 0.f, 0.f, 0.f, 0.f};
  for (int c = tid * 4; c < 2048; c += 1024) {
    float4 w4 = *(const float4*)(wv + c);
    float wj[4] = {w4.x, w4.y, w4.z, w4.w};
    float xv[8][4];
#pragma unroll
    for (int r = 0; r < 8; ++r) {
      float4 t = *(const float4*)(xb + (size_t)r * 2048 + c);
      xv[r][0] = t.x; xv[r][1] = t.y; xv[r][2] = t.z; xv[r][3] = t.w;
    }
#pragma unroll
    for (int j = 0; j < 4; ++j) {
      float x0 = xv[0][j], x1 = xv[1][j], x2 = xv[2][j], x3 = xv[3][j];
      float x4 = xv[4][j], x5 = xv[5][j], x6 = xv[6][j], x7 = xv[7][j];
      float t01 = x0 + x1, t23 = x2 + x3, t45 = x4 + x5, t67 = x6 + x7;
      float a = t01 + t23, bb = t45 + t67;
      float c3 = a + bb, d3 = a - bb, d2a = t01 - t23, d2b = t45 - t67;
      float d10 = x0 - x1, d11 = x2 - x3, d12 = x4 - x5, d13 = x6 - x7;
      sq[0] += c3 * c3;  sq[1] += d3 * d3;  sq[2] += d2a * d2a; sq[3] += d2b * d2b;
      sq[4] += d10 * d10; sq[5] += d11 * d11; sq[6] += d12 * d12; sq[7] += d13 * d13;
      float w = wj[j];
      pp[0] += x0 * w; pp[1] += x1 * w; pp[2] += x2 * w; pp[3] += x3 * w;
      pp[4] += x4 * w; pp[5] += x5 * w; pp[6] += x6 * w; pp[7] += x7 * w;
    }
  }
  __shared__ float sred[4][16];
  float vals[16];
#pragma unroll
  for (int q = 0; q < 8; ++q) vals[q] = sq[q];
#pragma unroll
  for (int q = 0; q < 8; ++q) vals[8 + q] = pp[q];
#pragma unroll
  for (int q = 0; q < 16; ++q) vals[q] = wave_sum(vals[q]);
  int lane = tid & 63, wid = tid >> 6;
  if (lane == 0) {
#pragma unroll
    for (int q = 0; q < 16; ++q) sred[wid][q] = vals[q];
  }
  __syncthreads();
  if (tid < 16) {
    float s = sred[0][tid] + sred[1][tid] + sred[2][tid] + sred[3][tid];
    if (tid < 8) {
      float scale = (tid < 2) ? 0.125f : ((tid < 4) ? 0.25f : 0.5f);
      int pos = (tid == 0) ? g : (tid == 1) ? (256 + g)
               : (tid < 4) ? (512 + 2 * g + (tid - 2)) : (1024 + 4 * g + (tid - 4));
      rho_us[b * NSEQ + pos] = sqrtf(s * scale);
    } else {
      pt[b * NSEQ + 8 * g + (tid - 8)] = s;
    }
  }
}

// ---------- kernel B: serial dynamics, one 512-thread block per batch ----------
__global__ __launch_bounds__(NT, 2) void kB(const float* __restrict__ rho_us,
                                            const float* __restrict__ pt,
                                            const float* __restrict__ phi,
                                            float* __restrict__ rho_f) {
  extern __shared__ float sm[];
  float* v    = sm;
  float* rho  = sm + NSEQ;
  float* u    = sm + 2 * NSEQ;
  float* up   = sm + 3 * NSEQ;
  float* y0   = sm + 4 * NSEQ;
  float* y1   = sm + 5 * NSEQ;
  float* y2   = sm + 6 * NSEQ;
  float* y3   = sm + 7 * NSEQ;
  float* yb   = sm + 8 * NSEQ;
  float* cb   = sm + 9 * NSEQ;
  float* red  = sm + 10 * NSEQ;   // 256 floats
  float* red2 = red + 256;        // 8 floats
  const int tid = threadIdx.x;
  const int b = blockIdx.x;
  int gen = 0;
  const float CFL_ = 0.4f;

  // ---- v = normalize(|dwt1d(per_token)| * sqrt(D)) ----
  {
    const float* ptb = pt + b * NSEQ;
    float vl[EPT]; float part = 0.f;
#pragma unroll
    for (int m = 0; m < EPT; ++m) {
      int s = tid + NT * m;
      float c;
      if (s < 256) {
        int r = s * 8;
        float t01 = ptb[r] + ptb[r+1], t23 = ptb[r+2] + ptb[r+3];
        float t45 = ptb[r+4] + ptb[r+5], t67 = ptb[r+6] + ptb[r+7];
        c = ((t01 + t23) + (t45 + t67)) * INV2R2;
      } else if (s < 512) {
        int r = (s - 256) * 8;
        float t01 = ptb[r] + ptb[r+1], t23 = ptb[r+2] + ptb[r+3];
        float t45 = ptb[r+4] + ptb[r+5], t67 = ptb[r+6] + ptb[r+7];
        c = ((t01 + t23) - (t45 + t67)) * INV2R2;
      } else if (s < 1024) {
        int r = (s - 512) * 4;
        c = ((ptb[r] + ptb[r+1]) - (ptb[r+2] + ptb[r+3])) * 0.5f;
      } else {
        int r = (s - 1024) * 2;
        c = (ptb[r] - ptb[r+1]) * INVR2;
      }
      float val = sqrtf(2048.0f * c * c) + EPSF;
      vl[m] = val; part += val;
    }
    float sv = block_sum(part, red, tid, gen);
    float inv = 1.0f / sv;
#pragma unroll
    for (int m = 0; m < EPT; ++m) v[tid + NT * m] = vl[m] * inv;
  }
  // ---- rho = normalize(rho_us) ----
  {
    const float* rb = rho_us + b * NSEQ;
    float rl[EPT]; float part = 0.f;
#pragma unroll
    for (int m = 0; m < EPT; ++m) { float r = rb[tid + NT * m] + EPSF; rl[m] = r; part += r; }
    float sr = block_sum(part, red, tid, gen);
    float inv = 1.f / sr;
#pragma unroll
    for (int m = 0; m < EPT; ++m) rho[tid + NT * m] = rl[m] * inv;
  }
  __syncthreads();

  for (int k = 0; k < 3; ++k) {
    // ---- reaction ----
    {
      float tl[EPT]; float part = 0.f;
#pragma unroll
      for (int m = 0; m < EPT; ++m) {
        int i = tid + NT * m;
        float r = rho[i];
        float t = r * expf(-0.1f * (phi[i] + logf(r)));
        float t2 = fabsf(t) + EPSF;
        tl[m] = t2; part += t2;
      }
      float s = block_sum(part, red, tid, gen);
      float inv = 1.f / s;
#pragma unroll
      for (int m = 0; m < EPT; ++m) rho[tid + NT * m] = tl[m] * inv;
    }
    // ---- mpc: u = grad1(v) ----
#pragma unroll
    for (int m = 0; m < EPT; ++m) {
      int i = tid + NT * m; int ip1 = (i + 1) & (NSEQ - 1);
      u[i] = v[ip1] - v[i];
    }
    for (int step = 0; step < 5; ++step) {
      conv_apply<0, true>(up, u, cb, red2, tid);   // up = leray(u), wave-max folded
      float mx = red2[0];
#pragma unroll
      for (int q = 1; q < 8; ++q) mx = fmaxf(mx, red2[q]);
      float dt = CFL_ / (mx + EPSF);
      // ---- forward rollout (ntie folded into t=0, wbar.r4 dot into t=3) ----
      float sarr[4]; float spv = 1.f; float ntie = 1.f, dot = 0.f;
#pragma unroll
      for (int t = 0; t < 4; ++t) {
        const float* yp = (t == 1) ? y0 : (t == 2) ? y1 : y2;
        float* yw = (t == 0) ? y0 : (t == 1) ? y1 : (t == 2) ? y2 : y3;
        float invp = 1.f / spv;
        float part2 = 0.f, aux = 0.f;
#pragma unroll
        for (int m = 0; m < EPT; ++m) {
          int i = tid + NT * m, im1 = (i - 1) & (NSEQ - 1), ip1 = (i + 1) & (NSEQ - 1);
          float ri, rim1, rip1;
          if (t == 0) { ri = rho[i]; rim1 = rho[im1]; rip1 = rho[ip1]; }
          else {
            ri   = (fabsf(yp[i])   + EPSF) * invp;
            rim1 = (fabsf(yp[im1]) + EPSF) * invp;
            rip1 = (fabsf(yp[ip1]) + EPSF) * invp;
          }
          float ui = up[i], um = up[im1];
          float Fi = ui > 0.f ? ui * ri : ui * rip1;
          float Fm = um > 0.f ? um * rim1 : um * ri;
          float yv = ri - dt * (Fi - Fm);
          yw[i] = yv;
          float ayv = fabsf(yv) + EPSF;
          part2 += ayv;
          if (t == 0) aux += (fabsf(ui) == mx) ? 1.f : 0.f;
          if (t == 3) aux += (1.f - v[i]) * 0.125f * ayv;
        }
        if (t == 0) { float o1, o2; block_sum2(part2, aux, red, tid, gen, o1, o2); sarr[0] = o1; ntie = o2; }
        else if (t == 3) { float o1, o2; block_sum2(part2, aux, red, tid, gen, o1, o2); sarr[3] = o1; dot = o2 / o1; }
        else sarr[t] = block_sum(part2, red, tid, gen);
        spv = sarr[t];
      }
      // ---- backward ----
      float wreg[EPT], upbar[EPT];
#pragma unroll
      for (int m = 0; m < EPT; ++m) {
        upbar[m] = 0.f;
        wreg[m] = (1.f - v[tid + NT * m]) * 0.125f;
      }
      float dtb_part = 0.f;
#pragma unroll
      for (int t = 3; t >= 0; --t) {
        const float* yt = (t == 0) ? y0 : (t == 1) ? y1 : (t == 2) ? y2 : y3;
        const float* yp = (t == 1) ? y0 : (t == 2) ? y1 : y2;
        float invst = 1.f / sarr[t];
        float invp = (t > 0) ? 1.f / sarr[t - 1] : 0.f;
        // pass A: ybar
#pragma unroll
        for (int m = 0; m < EPT; ++m) {
          int i = tid + NT * m;
          float yv = yt[i];
          float sg = (yv > 0.f) ? 1.f : ((yv < 0.f) ? -1.f : 0.f);
          yb[i] = sg * (wreg[m] - dot) * invst;
        }
        __syncthreads();
        // pass B: new wbar, upbar, dtbar, next dot
        float dotn = 0.f;
#pragma unroll
        for (int m = 0; m < EPT; ++m) {
          int i = tid + NT * m, im1 = (i - 1) & (NSEQ - 1), ip1 = (i + 1) & (NSEQ - 1);
          float ri, rim1, rip1;
          if (t == 0) { ri = rho[i]; rim1 = rho[im1]; rip1 = rho[ip1]; }
          else {
            ri   = (fabsf(yp[i])   + EPSF) * invp;
            rim1 = (fabsf(yp[im1]) + EPSF) * invp;
            rip1 = (fabsf(yp[ip1]) + EPSF) * invp;
          }
          float ui = up[i], um = up[im1];
          float ybi = yb[i], ybm = yb[im1], ybp = yb[ip1];
          float Fbi = dt * (ybp - ybi);
          float Fbm = dt * (ybi - ybm);
          float wn = ybi;
          if (ui > 0.f)    wn += Fbi * ui;
          if (!(um > 0.f)) wn += Fbm * um;
          upbar[m] += Fbi * (ui > 0.f ? ri : rip1);
          float Fi = ui > 0.f ? ui * ri : ui * rip1;
          float Fm = um > 0.f ? um * rim1 : um * ri;
          dtb_part -= ybi * (Fi - Fm);
          if (t > 0) dotn += wn * ri;
          wreg[m] = wn;
        }
        if (t > 0) dot = block_sum(dotn, red, tid, gen);
      }
      float dtbar = block_sum(dtb_part, red, tid, gen);
      float md = mx + EPSF;
      float mbar = dtbar * (-CFL_ / (md * md));
      float tiesc = mbar / ntie;
#pragma unroll
      for (int m = 0; m < EPT; ++m) {
        int i = tid + NT * m;
        float ui = up[i];
        if (fabsf(ui) == mx) {
          float sg = (ui > 0.f) ? 1.f : ((ui < 0.f) ? -1.f : 0.f);
          upbar[m] += tiesc * sg;
        }
        yb[i] = upbar[m];
      }
      conv_apply<1, false>(u, yb, cb, red2, tid);  // u -= 0.1 * leray(upbar)
    }
    // ---- outer: u = leray(u); dt; rho = normalize(advect(rho,u,dt,kappa)) ----
    conv_apply<0, true>(up, u, cb, red2, tid);
    float mx = red2[0];
#pragma unroll
    for (int q = 1; q < 8; ++q) mx = fmaxf(mx, red2[q]);
    float dt = CFL_ / (mx + EPSF);
    float kap = (k == 0) ? 0.01f : ((k == 1) ? 0.005f : 0.0f);
    float ylc[EPT]; float p2 = 0.f;
#pragma unroll
    for (int m = 0; m < EPT; ++m) {
      int i = tid + NT * m, im1 = (i - 1) & (NSEQ - 1), ip1 = (i + 1) & (NSEQ - 1);
      float ri = rho[i], rim1 = rho[im1], rip1 = rho[ip1];
      float ui = up[i], um = up[im1];
      float Fi = ui > 0.f ? ui * ri : ui * rip1;
      float Fm = um > 0.f ? um * rim1 : um * ri;
      float yv = ri - dt * (Fi - Fm) + kap * dt * (rip1 + rim1 - 2.f * ri);
      ylc[m] = yv; p2 += fabsf(yv) + EPSF;
    }
    float s = block_sum(p2, red, tid, gen);
    float inv = 1.f / s;
#pragma unroll
    for (int m = 0; m < EPT; ++m) rho[tid + NT * m] = (fabsf(ylc[m]) + EPSF) * inv;
    __syncthreads();
  }
  // ---- final: rho_f = (rho + 0.1 v)/sum ----
  {
    float fl[EPT]; float part = 0.f;
#pragma unroll
    for (int m = 0; m < EPT; ++m) {
      int i = tid + NT * m;
      float f = rho[i] + 0.1f * v[i];
      fl[m] = f; part += f;
    }
    float s = block_sum(part, red, tid, gen);
    float inv = 1.f / s;
#pragma unroll
    for (int m = 0; m < EPT; ++m) rho_f[b * NSEQ + tid + NT * m] = fl[m] * inv;
  }
}

// ---------- kernel C: out = IDWT3(rho_f[:,:,None] * band_w[BAND_IDX]) ----------
__global__ __launch_bounds__(256) void kC(const float* __restrict__ rho_f,
                                          const float* __restrict__ bw,
                                          float* __restrict__ out) {
  const int blk = blockIdx.x;
  const int b = blk >> 8;
  const int g = blk & 255;
  __shared__ float q[8];
  if (threadIdx.x < 8) {
    int t = threadIdx.x;
    const float* rb = rho_f + b * NSEQ;
    float val;
    if (t == 0)      val = rb[g] * INV2R2;
    else if (t == 1) val = rb[256 + g] * INV2R2;
    else if (t < 4)  val = rb[512 + 2 * g + (t - 2)] * 0.5f;
    else             val = rb[1024 + 4 * g + (t - 4)] * INVR2;
    q[t] = val;
  }
  __syncthreads();
  float* ob = out + (((size_t)b * NSEQ) + (size_t)g * 8) * 2048;
  for (int c = threadIdx.x * 4; c < 2048; c += 1024) {
    float4 B0 = *(const float4*)(bw + c);
    float4 B1 = *(const float4*)(bw + 2048 + c);
    float4 B2 = *(const float4*)(bw + 4096 + c);
    float4 B3 = *(const float4*)(bw + 6144 + c);
    float b0[4] = {B0.x, B0.y, B0.z, B0.w};
    float b1[4] = {B1.x, B1.y, B1.z, B1.w};
    float b2[4] = {B2.x, B2.y, B2.z, B2.w};
    float b3[4] = {B3.x, B3.y, B3.z, B3.w};
    float o[8][4];
#pragma unroll
    for (int cc = 0; cc < 4; ++cc) {
      float pa = q[0] * b0[cc], pd3 = q[1] * b1[cc];
      float p2a = q[2] * b2[cc], p2b = q[3] * b2[cc];
      float e0 = pa + pd3, e1 = pa - pd3;
      float f0 = e0 + p2a, f1 = e0 - p2a, f2 = e1 + p2b, f3 = e1 - p2b;
      float g0 = q[4] * b3[cc], g1 = q[5] * b3[cc], g2 = q[6] * b3[cc], g3 = q[7] * b3[cc];
      o[0][cc] = f0 + g0; o[1][cc] = f0 - g0;
      o[2][cc] = f1 + g1; o[3][cc] = f1 - g1;
      o[4][cc] = f2 + g2; o[5][cc] = f2 - g2;
      o[6][cc] = f3 + g3; o[7][cc] = f3 - g3;
    }
#pragma unroll
    for (int j = 0; j < 8; ++j) {
      float4 t = make_float4(o[j][0], o[j][1], o[j][2], o[j][3]);
      *(float4*)(ob + (size_t)j * 2048 + c) = t;
    }
  }
}

#define SMEM_B ((10 * NSEQ + 264) * sizeof(float))

extern "C" void kernel_launch(void* const* d_in, const int* in_sizes, int n_in,
                              void* d_out, int out_size, void* d_ws, size_t ws_size,
                              hipStream_t stream) {
  (void)in_sizes; (void)n_in; (void)out_size; (void)ws_size;
  const float* x   = (const float*)d_in[0];
  const float* wv  = (const float*)d_in[1];
  const float* phi = (const float*)d_in[2];
  const float* bw  = (const float*)d_in[3];
  float* out = (float*)d_out;
  float* rho_us = (float*)d_ws;
  float* pt     = rho_us + 8 * NSEQ;
  float* rho_f  = pt + 8 * NSEQ;

  hipFuncSetAttribute((const void*)kB, hipFuncAttributeMaxDynamicSharedMemorySize,
                      (int)SMEM_B);

  kA<<<dim3(2048), dim3(256), 0, stream>>>(x, wv, rho_us, pt);
  kB<<<dim3(8), dim3(NT), SMEM_B, stream>>>(rho_us, pt, phi, rho_f);
  kC<<<dim3(2048), dim3(256), 0, stream>>>(rho_f, bw, out);
}

// Round 4
// 208.937 us; speedup vs baseline: 2.3275x; 1.2108x over previous
//
#include <hip/hip_runtime.h>
#include <math.h>

#define NSEQ 2048
#define EPSF 1e-8f
#define INV2R2 0.35355339059327373f
#define INVR2  0.7071067811865476f
#define NT 512           // 8 waves, 2 per SIMD

// ---------- compile-time Leray conv taps ----------
// Jacobi: p_{n+1} = M p_n - 0.5 b, M = avg(neighbors), p_0 = 0, 50 iters
// => p = K * b, K = -0.5 * sum_{i=0}^{49} M^i   (circulant, support |j|<=49)
// leray(u) = u - grad1(K * div1(u)) = conv(LK, u); LK symmetric -> self-adjoint.
struct TapsF { float v[101]; };

constexpr TapsF make_tapsf() {
  TapsF t{};
  double K[99] = {};
  for (int j = -49; j <= 49; ++j) {
    int aj = j < 0 ? -j : j;
    double term = 1.0;
    for (int q = 0; q < aj; ++q) term *= 0.5;
    double sum = term;
    for (int i = aj + 2; i <= 49; i += 2) {
      int m = (i + j) / 2;
      term *= (double)((i - 1) * i) / (4.0 * (double)m * (double)(i - m));
      sum += term;
    }
    K[j + 49] = -0.5 * sum;
  }
  for (int o = -50; o <= 50; ++o) {
    double km1 = (o - 1 >= -49 && o - 1 <= 49) ? K[o - 1 + 49] : 0.0;
    double k0  = (o     >= -49 && o     <= 49) ? K[o + 49]     : 0.0;
    double kp1 = (o + 1 >= -49 && o + 1 <= 49) ? K[o + 1 + 49] : 0.0;
    double T = kp1 - 2.0 * k0 + km1;
    t.v[o + 50] = (float)(((o == 0) ? 1.0 : 0.0) - T);
  }
  return t;
}
constexpr TapsF LKF = make_tapsf();

// ---------- reduction helpers (512 threads = 8 waves) ----------
__device__ __forceinline__ float wave_sum(float x) {
#pragma unroll
  for (int m = 1; m < 64; m <<= 1) x += __shfl_xor(x, m, 64);
  return x;
}
__device__ __forceinline__ float wave_max(float x) {
#pragma unroll
  for (int m = 1; m < 64; m <<= 1) x = fmaxf(x, __shfl_xor(x, m, 64));
  return x;
}
__device__ __forceinline__ float block_sum(float x, float* red, int tid, int& gen) {
  float w = wave_sum(x);
  int slot = (gen & 7) << 5; gen++;
  if ((tid & 63) == 0) red[slot + (tid >> 6)] = w;
  __syncthreads();
  float s = 0.f;
#pragma unroll
  for (int q = 0; q < 8; ++q) s += red[slot + q];
  return s;
}
__device__ __forceinline__ void block_sum2(float a, float b, float* red, int tid, int& gen,
                                           float& oa, float& ob) {
  float wa = wave_sum(a), wb = wave_sum(b);
  int slot = (gen & 7) << 5; gen++;
  if ((tid & 63) == 0) { int w = tid >> 6; red[slot + w] = wa; red[slot + 16 + w] = wb; }
  __syncthreads();
  float sa = 0.f, sb = 0.f;
#pragma unroll
  for (int q = 0; q < 8; ++q) { sa += red[slot + q]; sb += red[slot + 16 + q]; }
  oa = sa; ob = sb;
}

// ---------- 101-tap circular conv: regs in, regs out, linear float4 staging ----------
// Stage: 1 ds_write_b128/thread. Window: 27 ds_read_b128/thread (contiguous,
// conflict-free). Output i=4*tid+j gets value at iv=i+(d-52-j) with tap (d-2-j).
__device__ __forceinline__ void conv_core(const float in[4], float acc[4],
                                          float* __restrict__ cb, int tid) {
  __syncthreads();   // WAR: previous conv's window reads vs our stage write
  *(float4*)(cb + (tid << 2)) = make_float4(in[0], in[1], in[2], in[3]);
  __syncthreads();
  acc[0] = 0.f; acc[1] = 0.f; acc[2] = 0.f; acc[3] = 0.f;
#pragma unroll
  for (int m = 0; m < 27; ++m) {
    float4 c4 = *(const float4*)(cb + (((tid - 13 + m) & 511) << 2));
    float cv[4] = {c4.x, c4.y, c4.z, c4.w};
#pragma unroll
    for (int jj = 0; jj < 4; ++jj) {
      const int d = 4 * m + jj;
#pragma unroll
      for (int j = 0; j < 4; ++j) {
        const int ti = d - 2 - j;
        if (ti >= 0 && ti <= 100) acc[j] = fmaf(LKF.v[ti], cv[jj], acc[j]);
      }
    }
  }
}

// ---------- kernel A: rho_unscaled (L2 of DWT rows) + per_token ----------
__global__ __launch_bounds__(256) void kA(const float* __restrict__ x,
                                          const float* __restrict__ wv,
                                          float* __restrict__ rho_us,
                                          float* __restrict__ pt) {
  const int blk = blockIdx.x;
  const int b = blk >> 8;
  const int g = blk & 255;
  const float* xb = x + (((size_t)b * NSEQ) + (size_t)g * 8) * 2048;
  const int tid = threadIdx.x;
  float sq[8] = {0.f, 0.f, 0.f, 0.f, 0.f, 0.f, 0.f, 0.f};
  float pp[8] = {0.f, 0.f, 0.f, 0.f, 0.f, 0.f, 0.f, 0.f};
  for (int c = tid * 4; c < 2048; c += 1024) {
    float4 w4 = *(const float4*)(wv + c);
    float wj[4] = {w4.x, w4.y, w4.z, w4.w};
    float xv[8][4];
#pragma unroll
    for (int r = 0; r < 8; ++r) {
      float4 t = *(const float4*)(xb + (size_t)r * 2048 + c);
      xv[r][0] = t.x; xv[r][1] = t.y; xv[r][2] = t.z; xv[r][3] = t.w;
    }
#pragma unroll
    for (int j = 0; j < 4; ++j) {
      float x0 = xv[0][j], x1 = xv[1][j], x2 = xv[2][j], x3 = xv[3][j];
      float x4 = xv[4][j], x5 = xv[5][j], x6 = xv[6][j], x7 = xv[7][j];
      float t01 = x0 + x1, t23 = x2 + x3, t45 = x4 + x5, t67 = x6 + x7;
      float a = t01 + t23, bb = t45 + t67;
      float c3 = a + bb, d3 = a - bb, d2a = t01 - t23, d2b = t45 - t67;
      float d10 = x0 - x1, d11 = x2 - x3, d12 = x4 - x5, d13 = x6 - x7;
      sq[0] += c3 * c3;  sq[1] += d3 * d3;  sq[2] += d2a * d2a; sq[3] += d2b * d2b;
      sq[4] += d10 * d10; sq[5] += d11 * d11; sq[6] += d12 * d12; sq[7] += d13 * d13;
      float w = wj[j];
      pp[0] += x0 * w; pp[1] += x1 * w; pp[2] += x2 * w; pp[3] += x3 * w;
      pp[4] += x4 * w; pp[5] += x5 * w; pp[6] += x6 * w; pp[7] += x7 * w;
    }
  }
  __shared__ float sred[4][16];
  float vals[16];
#pragma unroll
  for (int q = 0; q < 8; ++q) vals[q] = sq[q];
#pragma unroll
  for (int q = 0; q < 8; ++q) vals[8 + q] = pp[q];
#pragma unroll
  for (int q = 0; q < 16; ++q) vals[q] = wave_sum(vals[q]);
  int lane = tid & 63, wid = tid >> 6;
  if (lane == 0) {
#pragma unroll
    for (int q = 0; q < 16; ++q) sred[wid][q] = vals[q];
  }
  __syncthreads();
  if (tid < 16) {
    float s = sred[0][tid] + sred[1][tid] + sred[2][tid] + sred[3][tid];
    if (tid < 8) {
      float scale = (tid < 2) ? 0.125f : ((tid < 4) ? 0.25f : 0.5f);
      int pos = (tid == 0) ? g : (tid == 1) ? (256 + g)
               : (tid < 4) ? (512 + 2 * g + (tid - 2)) : (1024 + 4 * g + (tid - 4));
      rho_us[b * NSEQ + pos] = sqrtf(s * scale);
    } else {
      pt[b * NSEQ + 8 * g + (tid - 8)] = s;
    }
  }
}

// ---------- kernel B: serial dynamics, contiguous ownership (4 elems/thread) ----------
__global__ __launch_bounds__(NT, 2) void kB(const float* __restrict__ rho_us,
                                            const float* __restrict__ pt,
                                            const float* __restrict__ phi,
                                            float* __restrict__ rho_f) {
  __shared__ float cb[NSEQ];
  __shared__ float vE0[NT];
  __shared__ float rhoE0[NT], rhoE3[NT];
  __shared__ float upE3[NT];
  __shared__ float yE0[4][NT], yE3[4][NT];
  __shared__ float ybE0[NT], ybE3[NT];
  __shared__ float red[256];
  __shared__ float red2[8];

  const int tid = threadIdx.x;
  const int b = blockIdx.x;
  const int tm1 = (tid - 1) & (NT - 1);
  const int tp1 = (tid + 1) & (NT - 1);
  int gen = 0;
  const float CFL_ = 0.4f;

  // phi cache
  float4 phv = *(const float4*)(phi + 4 * tid);
  float phir[4] = {phv.x, phv.y, phv.z, phv.w};

  // ---- v = normalize(|dwt1d(per_token)| * sqrt(D)) ----
  float v_r[4]; float vp4c;
  {
    const float* ptb = pt + b * NSEQ;
    float vl[4]; float part = 0.f;
#pragma unroll
    for (int j = 0; j < 4; ++j) {
      float c;
      if (tid < 64) {
        int r = (4 * tid + j) * 8;
        float t01 = ptb[r] + ptb[r+1], t23 = ptb[r+2] + ptb[r+3];
        float t45 = ptb[r+4] + ptb[r+5], t67 = ptb[r+6] + ptb[r+7];
        c = ((t01 + t23) + (t45 + t67)) * INV2R2;
      } else if (tid < 128) {
        int r = (4 * (tid - 64) + j) * 8;
        float t01 = ptb[r] + ptb[r+1], t23 = ptb[r+2] + ptb[r+3];
        float t45 = ptb[r+4] + ptb[r+5], t67 = ptb[r+6] + ptb[r+7];
        c = ((t01 + t23) - (t45 + t67)) * INV2R2;
      } else if (tid < 256) {
        int r = (4 * (tid - 128) + j) * 4;
        c = ((ptb[r] + ptb[r+1]) - (ptb[r+2] + ptb[r+3])) * 0.5f;
      } else {
        int r = (4 * (tid - 256) + j) * 2;
        c = (ptb[r] - ptb[r+1]) * INVR2;
      }
      float val = sqrtf(2048.0f * c * c) + EPSF;
      vl[j] = val; part += val;
    }
    float sv = block_sum(part, red, tid, gen);
    float inv = 1.0f / sv;
#pragma unroll
    for (int j = 0; j < 4; ++j) v_r[j] = vl[j] * inv;
    vE0[tid] = v_r[0];
  }
  // ---- rho = normalize(rho_us) ----
  float rho_r[4];
  {
    float4 rv = *(const float4*)(rho_us + b * NSEQ + 4 * tid);
    float rl[4] = {rv.x + EPSF, rv.y + EPSF, rv.z + EPSF, rv.w + EPSF};
    float part = rl[0] + rl[1] + rl[2] + rl[3];
    float sr = block_sum(part, red, tid, gen);   // barrier also publishes vE0
    float inv = 1.f / sr;
#pragma unroll
    for (int j = 0; j < 4; ++j) rho_r[j] = rl[j] * inv;
    rhoE0[tid] = rho_r[0]; rhoE3[tid] = rho_r[3];
  }
  vp4c = vE0[tp1];   // v never changes; cache once

  for (int k = 0; k < 3; ++k) {
    // ---- reaction ----
    {
      float tl[4]; float part = 0.f;
#pragma unroll
      for (int j = 0; j < 4; ++j) {
        float r = rho_r[j];
        float t = r * expf(-0.1f * (phir[j] + logf(r)));
        float t2 = fabsf(t) + EPSF;
        tl[j] = t2; part += t2;
      }
      float s = block_sum(part, red, tid, gen);
      float inv = 1.f / s;
#pragma unroll
      for (int j = 0; j < 4; ++j) rho_r[j] = tl[j] * inv;
      rhoE0[tid] = rho_r[0]; rhoE3[tid] = rho_r[3];  // published by conv barriers
    }
    // ---- mpc: u = grad1(v) (registers only) ----
    float u_r[4];
    u_r[0] = v_r[1] - v_r[0]; u_r[1] = v_r[2] - v_r[1];
    u_r[2] = v_r[3] - v_r[2]; u_r[3] = vp4c - v_r[3];

    float up_r[4], y_r[4][4], ym1c[3], yp4c2[3];
    for (int step = 0; step < 5; ++step) {
      // ---- up = leray(u), max folded ----
      float accv[4];
      conv_core(u_r, accv, cb, tid);
#pragma unroll
      for (int j = 0; j < 4; ++j) up_r[j] = accv[j];
      upE3[tid] = up_r[3];
      {
        float mm = fmaxf(fmaxf(fabsf(accv[0]), fabsf(accv[1])),
                         fmaxf(fabsf(accv[2]), fabsf(accv[3])));
        mm = wave_max(mm);
        if ((tid & 63) == 0) red2[tid >> 6] = mm;
      }
      __syncthreads();
      float mx = red2[0];
#pragma unroll
      for (int q = 1; q < 8; ++q) mx = fmaxf(mx, red2[q]);
      float um1 = upE3[tm1];
      float rhom1 = rhoE3[tm1], rhop4 = rhoE0[tp1];
      float dt = CFL_ / (mx + EPSF);
      // ---- forward rollout (ntie folded into t=0, wbar.r4 dot into t=3) ----
      float sarr[4]; float spv = 1.f; float ntie = 1.f, dot = 0.f;
#pragma unroll
      for (int t = 0; t < 4; ++t) {
        float invp = 1.f / spv;
        if (t >= 1) { ym1c[t-1] = yE3[t-1][tm1]; yp4c2[t-1] = yE0[t-1][tp1]; }
        float rr[6];
        if (t == 0) {
          rr[0] = rhom1; rr[1] = rho_r[0]; rr[2] = rho_r[1];
          rr[3] = rho_r[2]; rr[4] = rho_r[3]; rr[5] = rhop4;
        } else {
          rr[0] = (fabsf(ym1c[t-1]) + EPSF) * invp;
#pragma unroll
          for (int j = 0; j < 4; ++j) rr[j+1] = (fabsf(y_r[t-1][j]) + EPSF) * invp;
          rr[5] = (fabsf(yp4c2[t-1]) + EPSF) * invp;
        }
        float part2 = 0.f, aux = 0.f;
#pragma unroll
        for (int j = 0; j < 4; ++j) {
          float ri = rr[j+1], rim1 = rr[j], rip1 = rr[j+2];
          float ui = up_r[j], um = j ? up_r[j-1] : um1;
          float Fi = ui > 0.f ? ui * ri : ui * rip1;
          float Fm = um > 0.f ? um * rim1 : um * ri;
          float yv = ri - dt * (Fi - Fm);
          y_r[t][j] = yv;
          float ayv = fabsf(yv) + EPSF;
          part2 += ayv;
          if (t == 0) aux += (fabsf(ui) == mx) ? 1.f : 0.f;
          if (t == 3) aux += (1.f - v_r[j]) * 0.125f * ayv;
        }
        yE0[t][tid] = y_r[t][0]; yE3[t][tid] = y_r[t][3];
        if (t == 0) { float o1, o2; block_sum2(part2, aux, red, tid, gen, o1, o2); sarr[0] = o1; ntie = o2; }
        else if (t == 3) { float o1, o2; block_sum2(part2, aux, red, tid, gen, o1, o2); sarr[3] = o1; dot = o2 / o1; }
        else sarr[t] = block_sum(part2, red, tid, gen);
        spv = sarr[t];
      }
      // ---- backward ----
      float wreg[4], upbar[4];
#pragma unroll
      for (int j = 0; j < 4; ++j) { wreg[j] = (1.f - v_r[j]) * 0.125f; upbar[j] = 0.f; }
      float dtb_part = 0.f;
#pragma unroll
      for (int t = 3; t >= 0; --t) {
        float invst = 1.f / sarr[t];
        float invp = (t > 0) ? 1.f / sarr[t-1] : 0.f;
        // pass A: yb from registers
        float yb_r[4];
#pragma unroll
        for (int j = 0; j < 4; ++j) {
          float yv = y_r[t][j];
          float sg = (yv > 0.f) ? 1.f : ((yv < 0.f) ? -1.f : 0.f);
          yb_r[j] = sg * (wreg[j] - dot) * invst;
        }
        ybE0[tid] = yb_r[0]; ybE3[tid] = yb_r[3];
        __syncthreads();
        float ybm1 = ybE3[tm1], ybp4 = ybE0[tp1];
        float rr[6];
        if (t == 0) {
          rr[0] = rhom1; rr[1] = rho_r[0]; rr[2] = rho_r[1];
          rr[3] = rho_r[2]; rr[4] = rho_r[3]; rr[5] = rhop4;
        } else {
          rr[0] = (fabsf(ym1c[t-1]) + EPSF) * invp;
#pragma unroll
          for (int j = 0; j < 4; ++j) rr[j+1] = (fabsf(y_r[t-1][j]) + EPSF) * invp;
          rr[5] = (fabsf(yp4c2[t-1]) + EPSF) * invp;
        }
        float dotn = 0.f;
#pragma unroll
        for (int j = 0; j < 4; ++j) {
          float ri = rr[j+1], rim1 = rr[j], rip1 = rr[j+2];
          float ui = up_r[j], um = j ? up_r[j-1] : um1;
          float ybi = yb_r[j];
          float ybm = j ? yb_r[j-1] : ybm1;
          float ybp = (j < 3) ? yb_r[j+1] : ybp4;
          float Fbi = dt * (ybp - ybi);
          float Fbm = dt * (ybi - ybm);
          float wn = ybi;
          if (ui > 0.f)    wn += Fbi * ui;
          if (!(um > 0.f)) wn += Fbm * um;
          upbar[j] += Fbi * (ui > 0.f ? ri : rip1);
          float Fi = ui > 0.f ? ui * ri : ui * rip1;
          float Fm = um > 0.f ? um * rim1 : um * ri;
          dtb_part -= ybi * (Fi - Fm);
          if (t > 0) dotn += wn * ri;
          wreg[j] = wn;
        }
        if (t > 0) dot = block_sum(dotn, red, tid, gen);
      }
      float dtbar = block_sum(dtb_part, red, tid, gen);
      float md = mx + EPSF;
      float mbar = dtbar * (-CFL_ / (md * md));
      float tiesc = mbar / ntie;
#pragma unroll
      for (int j = 0; j < 4; ++j) {
        float ui = up_r[j];
        if (fabsf(ui) == mx) {
          float sg = (ui > 0.f) ? 1.f : ((ui < 0.f) ? -1.f : 0.f);
          upbar[j] += tiesc * sg;
        }
      }
      // ---- u -= 0.1 * leray(upbar) (self-adjoint) ----
      conv_core(upbar, accv, cb, tid);
#pragma unroll
      for (int j = 0; j < 4; ++j) u_r[j] -= 0.1f * accv[j];
    }
    // ---- outer: u = leray(u); dt; rho = normalize(advect(rho,u,dt,kappa)) ----
    float accv[4];
    conv_core(u_r, accv, cb, tid);
#pragma unroll
    for (int j = 0; j < 4; ++j) up_r[j] = accv[j];
    upE3[tid] = up_r[3];
    {
      float mm = fmaxf(fmaxf(fabsf(accv[0]), fabsf(accv[1])),
                       fmaxf(fabsf(accv[2]), fabsf(accv[3])));
      mm = wave_max(mm);
      if ((tid & 63) == 0) red2[tid >> 6] = mm;
    }
    __syncthreads();
    float mx = red2[0];
#pragma unroll
    for (int q = 1; q < 8; ++q) mx = fmaxf(mx, red2[q]);
    float um1 = upE3[tm1];
    float rhom1 = rhoE3[tm1], rhop4 = rhoE0[tp1];
    float dt = CFL_ / (mx + EPSF);
    float kap = (k == 0) ? 0.01f : ((k == 1) ? 0.005f : 0.0f);
    float rr[6];
    rr[0] = rhom1; rr[1] = rho_r[0]; rr[2] = rho_r[1];
    rr[3] = rho_r[2]; rr[4] = rho_r[3]; rr[5] = rhop4;
    float ylc[4]; float p2 = 0.f;
#pragma unroll
    for (int j = 0; j < 4; ++j) {
      float ri = rr[j+1], rim1 = rr[j], rip1 = rr[j+2];
      float ui = up_r[j], um = j ? up_r[j-1] : um1;
      float Fi = ui > 0.f ? ui * ri : ui * rip1;
      float Fm = um > 0.f ? um * rim1 : um * ri;
      float yv = ri - dt * (Fi - Fm) + kap * dt * (rip1 + rim1 - 2.f * ri);
      ylc[j] = yv; p2 += fabsf(yv) + EPSF;
    }
    float s = block_sum(p2, red, tid, gen);
    float inv = 1.f / s;
#pragma unroll
    for (int j = 0; j < 4; ++j) rho_r[j] = (fabsf(ylc[j]) + EPSF) * inv;
    rhoE0[tid] = rho_r[0]; rhoE3[tid] = rho_r[3];
  }
  // ---- final: rho_f = (rho + 0.1 v)/sum ----
  {
    float fl[4]; float part = 0.f;
#pragma unroll
    for (int j = 0; j < 4; ++j) {
      float f = rho_r[j] + 0.1f * v_r[j];
      fl[j] = f; part += f;
    }
    float s = block_sum(part, red, tid, gen);
    float inv = 1.f / s;
    float4 o = make_float4(fl[0] * inv, fl[1] * inv, fl[2] * inv, fl[3] * inv);
    *(float4*)(rho_f + b * NSEQ + 4 * tid) = o;
  }
}

// ---------- kernel C: out = IDWT3(rho_f[:,:,None] * band_w[BAND_IDX]) ----------
__global__ __launch_bounds__(256) void kC(const float* __restrict__ rho_f,
                                          const float* __restrict__ bw,
                                          float* __restrict__ out) {
  const int blk = blockIdx.x;
  const int b = blk >> 8;
  const int g = blk & 255;
  __shared__ float q[8];
  if (threadIdx.x < 8) {
    int t = threadIdx.x;
    const float* rb = rho_f + b * NSEQ;
    float val;
    if (t == 0)      val = rb[g] * INV2R2;
    else if (t == 1) val = rb[256 + g] * INV2R2;
    else if (t < 4)  val = rb[512 + 2 * g + (t - 2)] * 0.5f;
    else             val = rb[1024 + 4 * g + (t - 4)] * INVR2;
    q[t] = val;
  }
  __syncthreads();
  float* ob = out + (((size_t)b * NSEQ) + (size_t)g * 8) * 2048;
  for (int c = threadIdx.x * 4; c < 2048; c += 1024) {
    float4 B0 = *(const float4*)(bw + c);
    float4 B1 = *(const float4*)(bw + 2048 + c);
    float4 B2 = *(const float4*)(bw + 4096 + c);
    float4 B3 = *(const float4*)(bw + 6144 + c);
    float b0[4] = {B0.x, B0.y, B0.z, B0.w};
    float b1[4] = {B1.x, B1.y, B1.z, B1.w};
    float b2[4] = {B2.x, B2.y, B2.z, B2.w};
    float b3[4] = {B3.x, B3.y, B3.z, B3.w};
    float o[8][4];
#pragma unroll
    for (int cc = 0; cc < 4; ++cc) {
      float pa = q[0] * b0[cc], pd3 = q[1] * b1[cc];
      float p2a = q[2] * b2[cc], p2b = q[3] * b2[cc];
      float e0 = pa + pd3, e1 = pa - pd3;
      float f0 = e0 + p2a, f1 = e0 - p2a, f2 = e1 + p2b, f3 = e1 - p2b;
      float g0 = q[4] * b3[cc], g1 = q[5] * b3[cc], g2 = q[6] * b3[cc], g3 = q[7] * b3[cc];
      o[0][cc] = f0 + g0; o[1][cc] = f0 - g0;
      o[2][cc] = f1 + g1; o[3][cc] = f1 - g1;
      o[4][cc] = f2 + g2; o[5][cc] = f2 - g2;
      o[6][cc] = f3 + g3; o[7][cc] = f3 - g3;
    }
#pragma unroll
    for (int j = 0; j < 8; ++j) {
      float4 t = make_float4(o[j][0], o[j][1], o[j][2], o[j][3]);
      *(float4*)(ob + (size_t)j * 2048 + c) = t;
    }
  }
}

extern "C" void kernel_launch(void* const* d_in, const int* in_sizes, int n_in,
                              void* d_out, int out_size, void* d_ws, size_t ws_size,
                              hipStream_t stream) {
  (void)in_sizes; (void)n_in; (void)out_size; (void)ws_size;
  const float* x   = (const float*)d_in[0];
  const float* wv  = (const float*)d_in[1];
  const float* phi = (const float*)d_in[2];
  const float* bw  = (const float*)d_in[3];
  float* out = (float*)d_out;
  float* rho_us = (float*)d_ws;
  float* pt     = rho_us + 8 * NSEQ;
  float* rho_f  = pt + 8 * NSEQ;

  kA<<<dim3(2048), dim3(256), 0, stream>>>(x, wv, rho_us, pt);
  kB<<<dim3(8), dim3(NT), 0, stream>>>(rho_us, pt, phi, rho_f);
  kC<<<dim3(2048), dim3(256), 0, stream>>>(rho_f, bw, out);
}